// Round 4
// baseline (86.910 us; speedup 1.0000x reference)
//
#include <hip/hip_runtime.h>
#include <hip/hip_bf16.h>
#include <math.h>

// ---------------- problem constants ----------------
namespace {
constexpr int BATCH = 4;
constexpr int IMG   = 192;
constexpr int PL    = IMG * IMG;
constexpr int NP1   = 4096;   // 64*64 full-res patches per image
constexpr int N96   = 1024;   // 32*32 patches at 96x96
constexpr int N48   = 256;    // 16*16 patches at 48x48
constexpr int MALL  = 5376;   // 4096 + 1024 + 256 candidate patches
constexpr int RS    = 28;     // fp32 row stride: 27 values + |c|^2 slot
constexpr int NCHUNK = 16;    // m-chunks for argmin partials
constexpr int TPC    = 21;    // 16-wide m-tiles per chunk (16*21*16 = 5376)

// gaussian kernel constants (float32 images of the numpy float32 values)
#define GA 0.27406862f   // gauss1d(1.0) edge
#define GB 0.45186276f   // gauss1d(1.0) center
#define RC 0.33277732f   // gauss1d(10.0) edge
#define RD 0.33444537f   // gauss1d(10.0) center

typedef __bf16 bf16x8 __attribute__((ext_vector_type(8)));
typedef float  f32x4  __attribute__((ext_vector_type(4)));

__device__ __forceinline__ void conv3(const float in[9], const float k[9], float out[9]) {
#pragma unroll
  for (int y = 0; y < 3; ++y)
#pragma unroll
    for (int x = 0; x < 3; ++x) {
      float s = 0.f;
#pragma unroll
      for (int i = 0; i < 3; ++i) {
        int yy = y + i - 1;
        if (yy < 0 || yy > 2) continue;
#pragma unroll
        for (int j = 0; j < 3; ++j) {
          int xx = x + j - 1;
          if (xx < 0 || xx > 2) continue;
          s = fmaf(k[i * 3 + j], in[yy * 3 + xx], s);
        }
      }
      out[y * 3 + x] = s;
    }
}

// gray -> normalized structure-tensor 27-vector + |c|^2 (of the normalized vec)
__device__ __forceinline__ void st_from_gray(const float gray[9], float stv[27], float& cs) {
  const float KX[9] = {GA * GA, 0.f, -GA * GA, GB * GA, 0.f, -GB * GA, GA * GA, 0.f, -GA * GA};
  const float KY[9] = {GA * GA, GA * GB, GA * GA, 0.f, 0.f, 0.f, -GA * GA, -GA * GB, -GA * GA};
  const float KS[9] = {RC * RC, RC * RD, RC * RC, RD * RC, RD * RD, RD * RC, RC * RC, RC * RD, RC * RC};
  float Ix[9], Iy[9];
  conv3(gray, KX, Ix);
  conv3(gray, KY, Iy);
  float Pxx[9], Pyy[9], Pxy[9];
#pragma unroll
  for (int t = 0; t < 9; ++t) {
    Pxx[t] = Ix[t] * Ix[t];
    Pyy[t] = Iy[t] * Iy[t];
    Pxy[t] = Ix[t] * Iy[t];
  }
  conv3(Pxx, KS, stv + 0);
  conv3(Pyy, KS, stv + 9);
  conv3(Pxy, KS, stv + 18);
  float s2 = 0.f;
#pragma unroll
  for (int d = 0; d < 27; ++d) s2 = fmaf(stv[d], stv[d], s2);
  float inv = 1.0f / (sqrtf(s2) + 1e-12f);
  float c = 0.f;
#pragma unroll
  for (int d = 0; d < 27; ++d) {
    stv[d] *= inv;
    c = fmaf(stv[d], stv[d], c);
  }
  cs = c;
}

// ---------------- bicubic taps (jax.image.resize, antialias=False) ----------------
__device__ __forceinline__ void mkw(int k0, int IS, float w[4], int k[4]) {
  const float W4[4] = {-0.0625f, 0.5625f, 0.5625f, -0.0625f};
  float ssum = 0.f;
#pragma unroll
  for (int u = 0; u < 4; ++u) {
    int kk = k0 + u;
    bool v = (kk >= 0) && (kk < IS);
    w[u] = v ? W4[u] : 0.f;
    k[u] = v ? kk : 0;
    ssum += w[u];
  }
  float inv = 1.f / ssum;  // interior: exactly 1.0
#pragma unroll
  for (int u = 0; u < 4; ++u) w[u] *= inv;
}

// resized-grayscale pixel straight from the 3-channel 192x192 image
// (resize and grayscale are both linear -> they commute)
__device__ __forceinline__ float bicubic_gray(const float* __restrict__ im,
                                              int i, int j, int step, int koff) {
  float wr[4], wc[4];
  int kr[4], kc[4];
  mkw(step * i + koff, IMG, wr, kr);
  mkw(step * j + koff, IMG, wc, kc);
  float acc = 0.f;
#pragma unroll
  for (int u = 0; u < 4; ++u) {
    float rs = 0.f;
#pragma unroll
    for (int v = 0; v < 4; ++v) {
      int o = kr[u] * IMG + kc[v];
      float r  = im[o];
      float g2 = im[PL + o];
      float bl = im[2 * PL + o];
      float gy = fmaf(0.114f, bl, fmaf(0.587f, g2, 0.2989f * r));
      rs = fmaf(wc[v], gy, rs);
    }
    acc = fmaf(wr[u], rs, acc);
  }
  return acc;
}

__device__ __forceinline__ unsigned bfpair(float a, float b) {
  __hip_bfloat16 ah = __float2bfloat16(a);
  __hip_bfloat16 bh = __float2bfloat16(b);
  return ((unsigned)__builtin_bit_cast(unsigned short, bh) << 16) |
         (unsigned)__builtin_bit_cast(unsigned short, ah);
}

// pack 27 values + tail into bf16 hi/lo row of 32 uints:
// uints 0..15 = hi pairs (k=0..31), 16..31 = lo pairs; k>=28 zero.
__device__ __forceinline__ void pack27(const float* __restrict__ v, float tail,
                                       unsigned* __restrict__ dst) {
  unsigned uh[16], ul[16];
#pragma unroll
  for (int p = 0; p < 16; ++p) {
    float a  = (2 * p < 27) ? v[2 * p] : 0.f;
    float bb = (2 * p + 1 < 27) ? v[2 * p + 1] : (2 * p + 1 == 27 ? tail : 0.f);
    __hip_bfloat16 ah = __float2bfloat16(a);
    __hip_bfloat16 bh = __float2bfloat16(bb);
    float af = __bfloat162float(ah), bf2 = __bfloat162float(bh);
    uh[p] = ((unsigned)__builtin_bit_cast(unsigned short, bh) << 16) |
            (unsigned)__builtin_bit_cast(unsigned short, ah);
    ul[p] = bfpair(a - af, bb - bf2);
  }
  uint4* d4 = reinterpret_cast<uint4*>(dst);
  d4[0] = make_uint4(uh[0], uh[1], uh[2], uh[3]);
  d4[1] = make_uint4(uh[4], uh[5], uh[6], uh[7]);
  d4[2] = make_uint4(uh[8], uh[9], uh[10], uh[11]);
  d4[3] = make_uint4(uh[12], uh[13], uh[14], uh[15]);
  d4[4] = make_uint4(ul[0], ul[1], ul[2], ul[3]);
  d4[5] = make_uint4(ul[4], ul[5], ul[6], ul[7]);
  d4[6] = make_uint4(ul[8], ul[9], ul[10], ul[11]);
  d4[7] = make_uint4(ul[12], ul[13], ul[14], ul[15]);
}

__device__ __forceinline__ void store_row28(float* __restrict__ dst, const float v[27], float tail) {
  float4* d4 = reinterpret_cast<float4*>(dst);
#pragma unroll
  for (int i = 0; i < 6; ++i)
    d4[i] = make_float4(v[4 * i], v[4 * i + 1], v[4 * i + 2], v[4 * i + 3]);
  d4[6] = make_float4(v[24], v[25], v[26], tail);
}

// ---------------- K1: main-scale patches (LDS-staged) + resized gray planes ----------------
// blocks [0,256): one (b, hb) strip of 64 main patches; loads coalesced via LDS.
// blocks [256,976): resized-gray pixels (96x96 and 48x48 planes), 64 px/block.
__global__ void __launch_bounds__(64) prep_main_kernel(
    const float* __restrict__ x, const float* __restrict__ gt,
    float* __restrict__ p1, float* __restrict__ p2c,
    unsigned* __restrict__ Qp, unsigned* __restrict__ Cp,
    float* __restrict__ g96, float* __restrict__ g48,
    unsigned* __restrict__ ctr) {
  const int bid = blockIdx.x;
  const int t = threadIdx.x;
  if (bid == 0 && t == 0) ctr[0] = 0;  // reset finalize ticket

  if (bid < 256) {
    const int b = bid >> 6, hb = bid & 63;
    __shared__ float lds[3456];  // [img2][ch3][row3][col192]
    for (int it = 0; it < 54; ++it) {
      int idx = it * 64 + t;
      int img = idx / 1728;
      int rem = idx - img * 1728;
      int c = rem / 576; rem -= c * 576;
      int r = rem / 192; int col = rem - r * 192;
      const float* sp = (img == 0) ? x : gt;
      lds[idx] = sp[(size_t)b * 3 * PL + (size_t)c * PL + (size_t)(hb * 3 + r) * IMG + col];
    }
    __syncthreads();

    float s1[27], s2[27];
    float cs1, cs2;
    {
      float gr[9];
#pragma unroll
      for (int y = 0; y < 3; ++y)
#pragma unroll
        for (int xx = 0; xx < 3; ++xx) {
          int o = y * 192 + 3 * t + xx;
          gr[y * 3 + xx] = fmaf(0.114f, lds[1152 + o], fmaf(0.587f, lds[576 + o], 0.2989f * lds[o]));
        }
      st_from_gray(gr, s1, cs1);
    }
    {
      float gr[9];
#pragma unroll
      for (int y = 0; y < 3; ++y)
#pragma unroll
        for (int xx = 0; xx < 3; ++xx) {
          int o = 1728 + y * 192 + 3 * t + xx;
          gr[y * 3 + xx] = fmaf(0.114f, lds[1152 + o], fmaf(0.587f, lds[576 + o], 0.2989f * lds[o]));
        }
      st_from_gray(gr, s2, cs2);
    }

    const int p = hb * 64 + t;
    const int g = b * NP1 + p;
    const size_t crow = (size_t)b * MALL + p;
    store_row28(p1 + (size_t)g * RS, s1, cs1);
    store_row28(p2c + crow * RS, s2, cs2);
    pack27(s2, -cs2, Cp + crow * 32);
    float qs[27];
#pragma unroll
    for (int d = 0; d < 27; ++d) qs[d] = s1[d] + s2[d];
    pack27(qs, 1.0f, Qp + (size_t)g * 32);
  } else {
    int pix = (bid - 256) * 64 + t;  // [0, 46080)
    if (pix < BATCH * 9216) {
      int b = pix / 9216, rem = pix - b * 9216;
      int i = rem / 96, j = rem - i * 96;
      g96[pix] = bicubic_gray(gt + (size_t)b * 3 * PL, i, j, 2, -1);
    } else {
      int q = pix - BATCH * 9216;
      int b = q / 2304, rem = q - b * 2304;
      int i = rem / 48, j = rem - i * 48;
      g48[q] = bicubic_gray(gt + (size_t)b * 3 * PL, i, j, 4, 0);
    }
  }
}

// ---------------- K2: scaled patches from the small gray planes ----------------
__global__ void __launch_bounds__(64) prep_scaled_kernel(
    const float* __restrict__ g96, const float* __restrict__ g48,
    float* __restrict__ p2c, unsigned* __restrict__ Cp) {
  int q = blockIdx.x * 64 + threadIdx.x;  // [0, 5120)
  const float* gp;
  int S, row;
  int hb, wb;
  if (q < BATCH * N96) {
    int b = q >> 10, p = q & (N96 - 1);
    hb = p >> 5; wb = p & 31;
    gp = g96 + (size_t)b * 9216;
    S = 96;
    row = b * MALL + NP1 + p;
  } else {
    int q2 = q - BATCH * N96;
    int b = q2 >> 8, p = q2 & (N48 - 1);
    hb = p >> 4; wb = p & 15;
    gp = g48 + (size_t)b * 2304;
    S = 48;
    row = b * MALL + NP1 + N96 + p;
  }
  float gr[9];
#pragma unroll
  for (int y = 0; y < 3; ++y)
#pragma unroll
    for (int xx = 0; xx < 3; ++xx)
      gr[y * 3 + xx] = gp[(size_t)(3 * hb + y) * S + 3 * wb + xx];
  float s[27];
  float cs;
  st_from_gray(gr, s, cs);
  store_row28(p2c + (size_t)row * RS, s, cs);
  pack27(s, -cs, Cp + (size_t)row * 32);
}

// ---------------- K3: MFMA argmax of t = 4 + q.c - |c|^2 via packed keys ----------------
// 1-wave blocks; wave owns 64 rows (4 n-tiles). Grid (64, NCHUNK, BATCH).
// D mapping (16x16x32): col = lane&15 (m within tile), row = (lane>>4)*4 + reg.
// key = (bits(score+4) & ~31) | (31 - iter): v_max_u32 running argmax;
// earlier iter wins ties (bigger low bits) => first-argmin semantics.
__global__ void __launch_bounds__(64, 4) argmin_mfma_kernel(
    const unsigned* __restrict__ Qp, const unsigned* __restrict__ Cp,
    unsigned* __restrict__ pkey, int* __restrict__ pidx) {
  const int lane = threadIdx.x;
  const int chunk = blockIdx.y;
  const int b = blockIdx.z;
  const int nbase = blockIdx.x * 64;
  const int lm = lane & 15, lg = lane >> 4;

  bf16x8 qh[4], ql[4];
#pragma unroll
  for (int t = 0; t < 4; ++t) {
    const unsigned* rp = Qp + ((size_t)(b * NP1 + nbase + t * 16 + lm)) * 32 + lg * 4;
    qh[t] = *reinterpret_cast<const bf16x8*>(rp);
    ql[t] = *reinterpret_cast<const bf16x8*>(rp + 16);
  }

  unsigned keys[4][4];
#pragma unroll
  for (int t = 0; t < 4; ++t)
#pragma unroll
    for (int r = 0; r < 4; ++r) keys[t][r] = 0u;

  const int tile0 = chunk * TPC;
  const unsigned* cr = Cp + ((size_t)(b * MALL + tile0 * 16 + lm)) * 32 + lg * 4;
#pragma unroll 3
  for (int i = 0; i < TPC; ++i) {
    bf16x8 ch = *reinterpret_cast<const bf16x8*>(cr);
    bf16x8 cl = *reinterpret_cast<const bf16x8*>(cr + 16);
    cr += 16 * 32;
#pragma unroll
    for (int t = 0; t < 4; ++t) {
      f32x4 a = {4.f, 4.f, 4.f, 4.f};  // +4 bias folded into C-init (scores in [-3,2])
      a = __builtin_amdgcn_mfma_f32_16x16x32_bf16(qh[t], ch, a, 0, 0, 0);
      a = __builtin_amdgcn_mfma_f32_16x16x32_bf16(ql[t], ch, a, 0, 0, 0);
      a = __builtin_amdgcn_mfma_f32_16x16x32_bf16(qh[t], cl, a, 0, 0, 0);
#pragma unroll
      for (int r = 0; r < 4; ++r) {
        unsigned kb = (__builtin_bit_cast(unsigned, (float)a[r]) & 0xFFFFFFE0u) |
                      (31u - (unsigned)i);
        keys[t][r] = keys[t][r] > kb ? keys[t][r] : kb;
      }
    }
  }

  // reduce (key, m) across the 16 lanes of each row-group; min m on key ties
#pragma unroll
  for (int t = 0; t < 4; ++t)
#pragma unroll
    for (int r = 0; r < 4; ++r) {
      unsigned k = keys[t][r];
      int m = (tile0 + (int)(31u - (k & 31u))) * 16 + lm;
#pragma unroll
      for (int mk = 1; mk < 16; mk <<= 1) {
        unsigned ok = (unsigned)__shfl_xor((int)k, mk, 64);
        int om = __shfl_xor(m, mk, 64);
        bool take = (ok > k) || (ok == k && om < m);
        k = take ? ok : k;
        m = take ? om : m;
      }
      if (lm == 0) {
        int rowi = nbase + t * 16 + lg * 4 + r;
        size_t o = ((size_t)(b * NP1 + rowi)) * NCHUNK + chunk;
        pkey[o] = k & 0xFFFFFFE0u;  // masked: cross-chunk compare, earlier chunk wins ties
        pidx[o] = m;
      }
    }
}

// ---------------- K4: combine partials, gather, L1 partials, ticketed final sum ----------------
__global__ void __launch_bounds__(128) finalize_kernel(
    const float* __restrict__ p1, const float* __restrict__ p2c,
    const unsigned* __restrict__ pkey, const int* __restrict__ pidx,
    float* __restrict__ bsum, unsigned* __restrict__ ctr, float* __restrict__ out) {
  int g = blockIdx.x * 128 + threadIdx.x;  // [0, BATCH*NP1)
  unsigned bk = 0u;
  int bi = 0;
  for (int ms = 0; ms < NCHUNK; ++ms) {
    unsigned k = pkey[(size_t)g * NCHUNK + ms];
    int ix = pidx[(size_t)g * NCHUNK + ms];
    bool gg = k > bk;  // strict > + ascending chunks => first-argmin tie-break
    bk = gg ? k : bk;
    bi = gg ? ix : bi;
  }
  int b = g >> 12;
  const float* a = p1 + (size_t)g * RS;
  const float* s2 = p2c + ((size_t)b * MALL + bi) * RS;
  float acc = 0.f;
#pragma unroll
  for (int d = 0; d < 27; ++d) acc += fabsf(a[d] - s2[d]);

  __shared__ float red[128];
  red[threadIdx.x] = acc;
  __syncthreads();
  for (int st = 64; st > 0; st >>= 1) {
    if (threadIdx.x < st) red[threadIdx.x] += red[threadIdx.x + st];
    __syncthreads();
  }
  if (threadIdx.x == 0) {
    __hip_atomic_store(&bsum[blockIdx.x], red[0], __ATOMIC_RELEASE, __HIP_MEMORY_SCOPE_AGENT);
    unsigned prev = __hip_atomic_fetch_add(ctr, 1u, __ATOMIC_ACQ_REL, __HIP_MEMORY_SCOPE_AGENT);
    if (prev == 127) {  // last block: deterministic ascending-order sum
      float s = 0.f;
      for (int i = 0; i < 128; ++i)
        s += __hip_atomic_load(&bsum[i], __ATOMIC_ACQUIRE, __HIP_MEMORY_SCOPE_AGENT);
      out[0] = s * (1.0f / 442368.0f);
    }
  }
}

}  // namespace

extern "C" void kernel_launch(void* const* d_in, const int* in_sizes, int n_in,
                              void* d_out, int out_size, void* d_ws, size_t ws_size,
                              hipStream_t stream) {
  const float* x  = (const float*)d_in[0];
  const float* gt = (const float*)d_in[1];
  float* out = (float*)d_out;

  // workspace layout (4-byte slots)
  float* ws = (float*)d_ws;
  float* p1   = ws;                                   // 4*4096*28
  float* p2c  = p1 + (size_t)BATCH * NP1 * RS;        // 4*5376*28
  unsigned* Qp = (unsigned*)(p2c + (size_t)BATCH * MALL * RS);    // 4*4096*32
  unsigned* Cp = Qp + (size_t)BATCH * NP1 * 32;       // 4*5376*32
  float* g96  = (float*)(Cp + (size_t)BATCH * MALL * 32);         // 4*9216
  float* g48  = g96 + (size_t)BATCH * 9216;                       // 4*2304
  unsigned* pkey = (unsigned*)(g48 + (size_t)BATCH * 2304);       // 4*4096*16
  int*   pidx   = (int*)(pkey + (size_t)BATCH * NP1 * NCHUNK);    // 4*4096*16
  float* bsum   = (float*)(pidx + (size_t)BATCH * NP1 * NCHUNK);  // 128
  unsigned* ctr = (unsigned*)(bsum + 128);                        // 1

  // K1: main-scale patches (256 blocks) + resized gray planes (720 blocks)
  prep_main_kernel<<<976, 64, 0, stream>>>(x, gt, p1, p2c, Qp, Cp, g96, g48, ctr);

  // K2: scaled patches from gray planes
  prep_scaled_kernel<<<80, 64, 0, stream>>>(g96, g48, p2c, Cp);

  // K3: MFMA chunked argmax
  {
    dim3 grid(64, NCHUNK, BATCH);
    argmin_mfma_kernel<<<grid, 64, 0, stream>>>(Qp, Cp, pkey, pidx);
  }

  // K4: combine chunks + L1 loss + ticketed deterministic final sum
  finalize_kernel<<<128, 128, 0, stream>>>(p1, p2c, pkey, pidx, bsum, ctr, out);
}

// Round 5
// 60.443 us; speedup vs baseline: 1.4379x; 1.4379x over previous
//
#include <hip/hip_runtime.h>
#include <hip/hip_bf16.h>
#include <math.h>

// ---------------- problem constants ----------------
namespace {
constexpr int BATCH = 4;
constexpr int IMG   = 192;
constexpr int PL    = IMG * IMG;
constexpr int NP1   = 4096;   // 64*64 full-res patches per image
constexpr int N96   = 1024;
constexpr int N48   = 256;
constexpr int MALL  = 5376;   // 4096 + 1024 + 256 candidate patches
constexpr int RS    = 28;     // fp32 row stride: 27 values + |c|^2 slot
constexpr int NCHUNK = 16;    // m-chunks for argmin partials
constexpr int TPC    = 21;    // 16-wide m-tiles per chunk (16*21*16 = 5376)

// gaussian kernel constants (float32 images of the numpy float32 values)
#define GA 0.27406862f   // gauss1d(1.0) edge
#define GB 0.45186276f   // gauss1d(1.0) center
#define RC 0.33277732f   // gauss1d(10.0) edge
#define RD 0.33444537f   // gauss1d(10.0) center

typedef __bf16 bf16x8 __attribute__((ext_vector_type(8)));
typedef float  f32x4  __attribute__((ext_vector_type(4)));

__device__ __forceinline__ void conv3(const float in[9], const float k[9], float out[9]) {
#pragma unroll
  for (int y = 0; y < 3; ++y)
#pragma unroll
    for (int x = 0; x < 3; ++x) {
      float s = 0.f;
#pragma unroll
      for (int i = 0; i < 3; ++i) {
        int yy = y + i - 1;
        if (yy < 0 || yy > 2) continue;
#pragma unroll
        for (int j = 0; j < 3; ++j) {
          int xx = x + j - 1;
          if (xx < 0 || xx > 2) continue;
          s = fmaf(k[i * 3 + j], in[yy * 3 + xx], s);
        }
      }
      out[y * 3 + x] = s;
    }
}

// ---------------- bicubic resize (jax.image.resize, antialias=False) ----------------
__device__ __forceinline__ void mkw(int k0, int IS, float w[4], int k[4]) {
  const float W4[4] = {-0.0625f, 0.5625f, 0.5625f, -0.0625f};
  float ssum = 0.f;
#pragma unroll
  for (int u = 0; u < 4; ++u) {
    int kk = k0 + u;
    bool v = (kk >= 0) && (kk < IS);
    w[u] = v ? W4[u] : 0.f;
    k[u] = v ? kk : 0;
    ssum += w[u];
  }
  float inv = 1.f / ssum;
#pragma unroll
  for (int u = 0; u < 4; ++u) w[u] *= inv;
}

__global__ void resize_kernel(const float* __restrict__ src, float* __restrict__ dst,
                              int OS, int step, int koff) {
  int o = blockIdx.x * blockDim.x + threadIdx.x;
  int total = BATCH * 3 * OS * OS;
  if (o >= total) return;
  int j = o % OS;
  int i = (o / OS) % OS;
  int bc = o / (OS * OS);
  const float* s = src + (size_t)bc * IMG * IMG;
  float wr[4], wc[4];
  int kr[4], kc[4];
  mkw(step * i + koff, IMG, wr, kr);
  mkw(step * j + koff, IMG, wc, kc);
  float acc = 0.f;
#pragma unroll
  for (int u = 0; u < 4; ++u) {
    const float* srow = s + (size_t)kr[u] * IMG;
    float rsum = 0.f;
#pragma unroll
    for (int v = 0; v < 4; ++v) rsum = fmaf(wc[v], srow[kc[v]], rsum);
    acc = fmaf(wr[u], rsum, acc);
  }
  dst[o] = acc;
}

// ---------------- patch -> structure tensor -> normalized 27-vector ----------------
template <bool WRITE_C>
__global__ void patch_kernel(const float* __restrict__ img, int H, int Wb,
                             float* __restrict__ dst, int dstBstride, int dstOff,
                             int npp) {
  int g = blockIdx.x * blockDim.x + threadIdx.x;
  if (g >= BATCH * npp) return;
  int b = g / npp, p = g - b * npp;
  int hb = p / Wb, wb = p - hb * Wb;
  const size_t plane = (size_t)H * H;
  const float* base = img + (size_t)b * 3 * plane + (size_t)(hb * 3) * H + wb * 3;

  float gray[9];
#pragma unroll
  for (int y = 0; y < 3; ++y)
#pragma unroll
    for (int x = 0; x < 3; ++x) {
      float r  = base[(size_t)y * H + x];
      float gg = base[plane + (size_t)y * H + x];
      float bl = base[2 * plane + (size_t)y * H + x];
      gray[y * 3 + x] = fmaf(0.114f, bl, fmaf(0.587f, gg, 0.2989f * r));
    }

  const float KX[9] = {GA * GA, 0.f, -GA * GA, GB * GA, 0.f, -GB * GA, GA * GA, 0.f, -GA * GA};
  const float KY[9] = {GA * GA, GA * GB, GA * GA, 0.f, 0.f, 0.f, -GA * GA, -GA * GB, -GA * GA};
  const float KS[9] = {RC * RC, RC * RD, RC * RC, RD * RC, RD * RD, RD * RC, RC * RC, RC * RD, RC * RC};

  float Ix[9], Iy[9];
  conv3(gray, KX, Ix);
  conv3(gray, KY, Iy);
  float Pxx[9], Pyy[9], Pxy[9];
#pragma unroll
  for (int t = 0; t < 9; ++t) {
    Pxx[t] = Ix[t] * Ix[t];
    Pyy[t] = Iy[t] * Iy[t];
    Pxy[t] = Ix[t] * Iy[t];
  }
  float st[27];
  conv3(Pxx, KS, st + 0);
  conv3(Pyy, KS, st + 9);
  conv3(Pxy, KS, st + 18);

  float s2 = 0.f;
#pragma unroll
  for (int d = 0; d < 27; ++d) s2 = fmaf(st[d], st[d], s2);
  float nrm = sqrtf(s2) + 1e-12f;
  float inv = 1.0f / nrm;

  float* orow = dst + ((size_t)b * dstBstride + dstOff + p) * RS;
  float cs = 0.f;
#pragma unroll
  for (int d = 0; d < 27; ++d) {
    float v = st[d] * inv;
    orow[d] = v;
    cs = fmaf(v, v, cs);
  }
  if (WRITE_C) orow[27] = cs;
}

// ---------------- pack Q=p1+p2 and C=p2c into MFMA-fragment-major bf16 tiles ----------
// Tile = 16 rows = 512 uints (2 KB). Within a tile:
//   hi half (uints 0..255):  chunk lg in 0..3, row rl in 0..15 -> uint4 at (lg*16+rl)*4
//   lo half (uints 256..511): same layout.
// In the argmin kernel lane l (= lg*16+lm) reads uint4 at tile_base + l*4 (hi) and
// tile_base + 256 + l*4 (lo) -> both loads fully coalesced (64 x 16B contiguous).
// k=27 carries [1.0 | -|c|^2] so the MFMA computes q.c - |c|^2 directly.
__global__ void pack_kernel(const float* __restrict__ p1, const float* __restrict__ p2c,
                            unsigned* __restrict__ Qp, unsigned* __restrict__ Cp) {
  int g = blockIdx.x * 256 + threadIdx.x;
  const int NC = BATCH * MALL;
  float v[28];
  unsigned* base;
  int rl;
  if (g < NC) {
    const float* s = p2c + (size_t)g * RS;
#pragma unroll
    for (int d = 0; d < 27; ++d) v[d] = s[d];
    v[27] = -s[27];
    base = Cp + (size_t)(g >> 4) * 512;
    rl = g & 15;
  } else {
    int q = g - NC;
    if (q >= BATCH * NP1) return;
    int b = q >> 12, n = q & (NP1 - 1);
    const float* a = p1 + (size_t)q * RS;
    const float* c = p2c + ((size_t)b * MALL + n) * RS;
#pragma unroll
    for (int d = 0; d < 27; ++d) v[d] = a[d] + c[d];
    v[27] = 1.0f;
    base = Qp + (size_t)(q >> 4) * 512;
    rl = q & 15;
  }

  unsigned uh[16], ul[16];
#pragma unroll
  for (int p = 0; p < 16; ++p) {
    float a  = (2 * p < 28) ? v[2 * p] : 0.f;
    float bb = (2 * p + 1 < 28) ? v[2 * p + 1] : 0.f;
    __hip_bfloat16 ah = __float2bfloat16(a);
    __hip_bfloat16 bh = __float2bfloat16(bb);
    float af = __bfloat162float(ah), bf2 = __bfloat162float(bh);
    __hip_bfloat16 al = __float2bfloat16(a - af);
    __hip_bfloat16 bl = __float2bfloat16(bb - bf2);
    uh[p] = ((unsigned)__builtin_bit_cast(unsigned short, bh) << 16) |
            (unsigned)__builtin_bit_cast(unsigned short, ah);
    ul[p] = ((unsigned)__builtin_bit_cast(unsigned short, bl) << 16) |
            (unsigned)__builtin_bit_cast(unsigned short, al);
  }
#pragma unroll
  for (int lg = 0; lg < 4; ++lg) {
    *reinterpret_cast<uint4*>(base + (size_t)(lg * 16 + rl) * 4) =
        make_uint4(uh[4 * lg], uh[4 * lg + 1], uh[4 * lg + 2], uh[4 * lg + 3]);
    *reinterpret_cast<uint4*>(base + 256 + (size_t)(lg * 16 + rl) * 4) =
        make_uint4(ul[4 * lg], ul[4 * lg + 1], ul[4 * lg + 2], ul[4 * lg + 3]);
  }
}

// ---------------- MFMA argmax of t = 4 + q.c - |c|^2 via packed keys ----------------
// 256-thread blocks, 4 waves; wave w owns rows nbase..nbase+63 (4 n-tiles).
// Grid (16, NCHUNK, BATCH). D mapping (16x16x32): col=lane&15 (m), row=(lane>>4)*4+reg.
// key = (bits(score+4) & ~31) | (31 - iter): v_max_u32 running argmax; earlier
// iter wins ties (bigger low bits) => first-argmin semantics after chunk combine.
__global__ void __launch_bounds__(256, 2) argmin_mfma_kernel(
    const unsigned* __restrict__ Qp, const unsigned* __restrict__ Cp,
    unsigned* __restrict__ pkey, int* __restrict__ pidx) {
  const int lane = threadIdx.x & 63;
  const int w = threadIdx.x >> 6;
  const int chunk = blockIdx.y;
  const int b = blockIdx.z;
  const int nbase = blockIdx.x * 256 + w * 64;
  const int lm = lane & 15, lg = lane >> 4;

  // coalesced fragment loads: tile t of this wave's 4 n-tiles, lane*16B
  bf16x8 qh[4], ql[4];
#pragma unroll
  for (int t = 0; t < 4; ++t) {
    const unsigned* tb = Qp + (size_t)((b * NP1 + nbase) >> 4) * 512 + (size_t)t * 512 + lane * 4;
    qh[t] = *reinterpret_cast<const bf16x8*>(tb);
    ql[t] = *reinterpret_cast<const bf16x8*>(tb + 256);
  }

  unsigned keys[4][4];
#pragma unroll
  for (int t = 0; t < 4; ++t)
#pragma unroll
    for (int r = 0; r < 4; ++r) keys[t][r] = 0u;

  const int tile0 = chunk * TPC;
  const unsigned* cb = Cp + (size_t)(b * (MALL >> 4) + tile0) * 512 + lane * 4;
  for (int i = 0; i < TPC; ++i) {
    bf16x8 ch = *reinterpret_cast<const bf16x8*>(cb);
    bf16x8 cl = *reinterpret_cast<const bf16x8*>(cb + 256);
    cb += 512;
    const unsigned tag = 31u - (unsigned)i;
#pragma unroll
    for (int t = 0; t < 4; ++t) {
      f32x4 a = {4.f, 4.f, 4.f, 4.f};  // +4 bias: scores in [-3,2] -> [1,6] (positive)
      a = __builtin_amdgcn_mfma_f32_16x16x32_bf16(qh[t], ch, a, 0, 0, 0);
      a = __builtin_amdgcn_mfma_f32_16x16x32_bf16(ql[t], ch, a, 0, 0, 0);
      a = __builtin_amdgcn_mfma_f32_16x16x32_bf16(qh[t], cl, a, 0, 0, 0);
#pragma unroll
      for (int r = 0; r < 4; ++r) {
        unsigned kb = (__builtin_bit_cast(unsigned, (float)a[r]) & 0xFFFFFFE0u) | tag;
        keys[t][r] = keys[t][r] > kb ? keys[t][r] : kb;
      }
    }
  }

  // reduce (key, m) across the 16 lanes of each row-group; min m on key ties
#pragma unroll
  for (int t = 0; t < 4; ++t)
#pragma unroll
    for (int r = 0; r < 4; ++r) {
      unsigned k = keys[t][r];
      int m = (tile0 + (int)(31u - (k & 31u))) * 16 + lm;
#pragma unroll
      for (int mk = 1; mk < 16; mk <<= 1) {
        unsigned ok = (unsigned)__shfl_xor((int)k, mk, 64);
        int om = __shfl_xor(m, mk, 64);
        bool take = (ok > k) || (ok == k && om < m);
        k = take ? ok : k;
        m = take ? om : m;
      }
      if (lm == 0) {
        int row = nbase + t * 16 + lg * 4 + r;
        size_t o = ((size_t)(b * NP1 + row)) * NCHUNK + chunk;
        pkey[o] = k & 0xFFFFFFE0u;  // masked: cross-chunk strict '>' keeps earliest chunk
        pidx[o] = m;
      }
    }
}

// ---------------- combine partials, gather selected patch, L1 partial sums ----------------
__global__ void finalize_kernel(const float* __restrict__ p1, const float* __restrict__ p2c,
                                const unsigned* __restrict__ pkey, const int* __restrict__ pidx,
                                float* __restrict__ bsum) {
  int g = blockIdx.x * 256 + threadIdx.x;  // [0, BATCH*NP1)
  unsigned bk = 0u;
  int bi = 0;
  for (int ms = 0; ms < NCHUNK; ++ms) {
    unsigned k = pkey[(size_t)g * NCHUNK + ms];
    int ix = pidx[(size_t)g * NCHUNK + ms];
    bool gg = k > bk;  // strict > + ascending chunks => first-argmin tie-break
    bk = gg ? k : bk;
    bi = gg ? ix : bi;
  }
  int b = g >> 12;
  const float* a = p1 + (size_t)g * RS;
  const float* s2 = p2c + ((size_t)b * MALL + bi) * RS;
  float acc = 0.f;
#pragma unroll
  for (int d = 0; d < 27; ++d) acc += fabsf(a[d] - s2[d]);

  __shared__ float red[256];
  red[threadIdx.x] = acc;
  __syncthreads();
  for (int st = 128; st > 0; st >>= 1) {
    if (threadIdx.x < st) red[threadIdx.x] += red[threadIdx.x + st];
    __syncthreads();
  }
  if (threadIdx.x == 0) bsum[blockIdx.x] = red[0];
}

__global__ void final_sum_kernel(const float* __restrict__ bsum, float* __restrict__ out) {
  __shared__ float red[64];
  red[threadIdx.x] = bsum[threadIdx.x];
  __syncthreads();
  for (int st = 32; st > 0; st >>= 1) {
    if (threadIdx.x < st) red[threadIdx.x] += red[threadIdx.x + st];
    __syncthreads();
  }
  if (threadIdx.x == 0) out[0] = red[0] * (1.0f / 442368.0f);
}

}  // namespace

extern "C" void kernel_launch(void* const* d_in, const int* in_sizes, int n_in,
                              void* d_out, int out_size, void* d_ws, size_t ws_size,
                              hipStream_t stream) {
  const float* x  = (const float*)d_in[0];
  const float* gt = (const float*)d_in[1];
  float* out = (float*)d_out;

  // workspace layout (4-byte slots)
  float* ws = (float*)d_ws;
  float* p1   = ws;                                   // 4*4096*28
  float* p2c  = p1 + (size_t)BATCH * NP1 * RS;        // 4*5376*28
  float* r96  = p2c + (size_t)BATCH * MALL * RS;      // 110592
  float* r48  = r96 + (size_t)BATCH * 3 * 96 * 96;    // 27648
  unsigned* Qp = (unsigned*)(r48 + (size_t)BATCH * 3 * 48 * 48);  // 4*4096*32
  unsigned* Cp = Qp + (size_t)BATCH * NP1 * 32;       // 4*5376*32
  unsigned* pkey = (unsigned*)(Cp + (size_t)BATCH * MALL * 32);   // 4*4096*16
  int*   pidx   = (int*)(pkey + (size_t)BATCH * NP1 * NCHUNK);    // 4*4096*16
  float* bsum   = (float*)(pidx + (size_t)BATCH * NP1 * NCHUNK);  // 64

  // resize gt -> 96 and 48 (bicubic, antialias=False)
  {
    int tot = BATCH * 3 * 96 * 96;
    resize_kernel<<<(tot + 255) / 256, 256, 0, stream>>>(gt, r96, 96, 2, -1);
  }
  {
    int tot = BATCH * 3 * 48 * 48;
    resize_kernel<<<(tot + 255) / 256, 256, 0, stream>>>(gt, r48, 48, 4, 0);
  }

  // patches
  patch_kernel<false><<<(BATCH * NP1 + 255) / 256, 256, 0, stream>>>(
      x, IMG, 64, p1, NP1, 0, NP1);
  patch_kernel<true><<<(BATCH * NP1 + 255) / 256, 256, 0, stream>>>(
      gt, IMG, 64, p2c, MALL, 0, NP1);
  patch_kernel<true><<<(BATCH * 1024 + 255) / 256, 256, 0, stream>>>(
      r96, 96, 32, p2c, MALL, NP1, 1024);
  patch_kernel<true><<<(BATCH * 256 + 255) / 256, 256, 0, stream>>>(
      r48, 48, 16, p2c, MALL, NP1 + 1024, 256);

  // pack fragment-major bf16 operands (Q = p1+p2 with k27=1; C = p2c with k27=-|c|^2)
  {
    int tot = BATCH * (MALL + NP1);
    pack_kernel<<<(tot + 255) / 256, 256, 0, stream>>>(p1, p2c, Qp, Cp);
  }

  // MFMA chunked argmax (coalesced fragment loads)
  {
    dim3 grid(16, NCHUNK, BATCH);
    argmin_mfma_kernel<<<grid, 256, 0, stream>>>(Qp, Cp, pkey, pidx);
  }

  // finalize: combine chunks + L1 loss partials
  finalize_kernel<<<(BATCH * NP1) / 256, 256, 0, stream>>>(p1, p2c, pkey, pidx, bsum);
  final_sum_kernel<<<1, 64, 0, stream>>>(bsum, out);
}